// Round 2
// baseline (183.338 us; speedup 1.0000x reference)
//
#include <hip/hip_runtime.h>
#include <stdint.h>

#define HW 9216
#define CDIM 128
#define WIDTH 96
#define BATCH 2

// 1/(sqrt(128)*0.1) * log2(e): folded into Q so epilogue is a bare exp2
#define QSCALE 1.2753324954171245f

typedef _Float16 half8 __attribute__((ext_vector_type(8)));
typedef float float4v __attribute__((ext_vector_type(4)));
typedef float float2v __attribute__((ext_vector_type(2)));

// ---------------------------------------------------------------------------
// Kernel 1: L2-normalize over channel dim, write fp16 in [B][HW][C] layout.
// Q additionally scaled by QSCALE so attn epilogue needs no multiplies.
// ---------------------------------------------------------------------------
__global__ __launch_bounds__(256) void norm_kernel(const float* __restrict__ fL,
                                                   const float* __restrict__ fR,
                                                   _Float16* __restrict__ Qh,
                                                   _Float16* __restrict__ Kh)
{
    const float* src = (blockIdx.y == 0) ? fL : fR;
    _Float16* dst    = (blockIdx.y == 0) ? Qh : Kh;
    const float outScale = (blockIdx.y == 0) ? QSCALE : 1.0f;
    int tid = blockIdx.x * 256 + threadIdx.x;   // 0 .. B*HW-1 (grid sized exactly)
    int b = tid / HW, pos = tid % HW;
    const float* p = src + (size_t)b * CDIM * HW + pos;

    float ss = 0.f;
    #pragma unroll 8
    for (int c = 0; c < CDIM; ++c) { float v = p[(size_t)c * HW]; ss += v * v; }
    float scale = outScale / fmaxf(sqrtf(ss), 1e-6f);

    _Float16* o = dst + (size_t)tid * CDIM;
    #pragma unroll
    for (int c8 = 0; c8 < CDIM / 8; ++c8) {
        _Float16 tmp[8];
        #pragma unroll
        for (int j = 0; j < 8; ++j)
            tmp[j] = (_Float16)(p[(size_t)(c8 * 8 + j) * HW] * scale);
        *(uint4*)(o + c8 * 8) = *(const uint4*)tmp;
    }
}

// ---------------------------------------------------------------------------
// Kernel 2: fused correlation + softmax-accumulate.
// Block: 128 q-rows x 128 keys, 4 waves x (64x64). Q fragments live in
// registers (loaded once). K double-buffered in LDS (2 x 32 KB, unpadded,
// XOR-chunk swizzle for conflict-free reads), staged via global_load_lds
// issued before the VALU epilogue -> latency hidden, ONE barrier per tile.
// No online max needed: |logit2| <= 1.28, exp2 in [0.41, 2.42].
// ---------------------------------------------------------------------------
__global__ __launch_bounds__(256, 2) void attn_kernel(const _Float16* __restrict__ Qh,
                                                      const _Float16* __restrict__ Kh,
                                                      float4* __restrict__ part)
{
    __shared__ _Float16 Ks[2][128 * 128];   // 2 x 32 KB

    const int qt = blockIdx.x, split = blockIdx.y, b = blockIdx.z;
    const int t = threadIdx.x;
    const int lane = t & 63, wave = t >> 6;
    const int wq = wave >> 1, wk = wave & 1;          // 2x2 wave grid over 128x128
    const int lane15 = lane & 15, quad = lane >> 4;

    // ---- Q fragments direct from global (once per block) ----
    half8 af[4][4];   // [mt][kc]
    {
        const char* qb = (const char*)(Qh +
            ((size_t)(b * HW + qt * 128 + wq * 64 + lane15)) * CDIM);
        #pragma unroll
        for (int mt = 0; mt < 4; ++mt)
            #pragma unroll
            for (int kc = 0; kc < 4; ++kc)
                af[mt][kc] = *(const half8*)(qb + mt * 16 * 256 + kc * 64 + quad * 16);
    }

    const char* kgb = (const char*)(Kh + (size_t)b * HW * CDIM);

    // stage one 128x128 K-tile into Ks[buf]: wave w does rows [w*32, w*32+32).
    // dest is linear (global_load_lds constraint); source chunk is XOR-swizzled
    // so LDS[row][c'] = K[row][c' ^ (row&15)] -> conflict-free fragment reads.
    auto stage = [&](int kbase, int buf) {
        #pragma unroll
        for (int i = 0; i < 8; ++i) {
            int rlocal = wave * 32 + i * 4 + quad;                 // 0..127
            int schunk = lane15 ^ ((i * 4 + quad) & 15);
            const void* src = kgb + (size_t)(kbase + rlocal) * 256 + schunk * 16;
            _Float16* dstv = &Ks[buf][(wave * 32 + i * 4) * 128];  // wave-uniform
            __builtin_amdgcn_global_load_lds(
                (const __attribute__((address_space(1))) uint32_t*)src,
                (__attribute__((address_space(3))) uint32_t*)dstv, 16, 0, 0);
        }
    };

    float2v l2[8], ax2[8], ay2[8], mx2[8];   // p = mt*2 + rpair
    #pragma unroll
    for (int p = 0; p < 8; ++p) {
        l2[p] = (float2v)0.f; ax2[p] = (float2v)0.f; ay2[p] = (float2v)0.f;
        mx2[p] = (float2v)(-1.0e30f);
    }

    stage(split * 1152, 0);
    __syncthreads();

    for (int kt = 0; kt < 9; ++kt) {
        const int cur = kt & 1;
        const int kbase = split * 1152 + kt * 128;

        float4v acc[4][4];
        #pragma unroll
        for (int mt = 0; mt < 4; ++mt)
            #pragma unroll
            for (int nt = 0; nt < 4; ++nt)
                acc[mt][nt] = (float4v)0.f;

        const char* kb = (const char*)&Ks[cur][0];
        #pragma unroll
        for (int kc = 0; kc < 4; ++kc) {
            half8 bf[4];
            #pragma unroll
            for (int nt = 0; nt < 4; ++nt)
                bf[nt] = *(const half8*)(kb +
                    ((wk * 64 + nt * 16 + lane15) << 8) +
                    (((kc * 4 + quad) ^ lane15) << 4));
            #pragma unroll
            for (int mt = 0; mt < 4; ++mt)
                #pragma unroll
                for (int nt = 0; nt < 4; ++nt)
                    acc[mt][nt] = __builtin_amdgcn_mfma_f32_16x16x32_f16(
                        af[mt][kc], bf[nt], acc[mt][nt], 0, 0, 0);
        }

        // async prefetch of next tile overlaps the VALU epilogue below
        if (kt < 8) stage(kbase + 128, 1 - cur);

        // ---- fused softmax-accumulate epilogue (packed fp32 pairs) ----
        #pragma unroll
        for (int nt = 0; nt < 4; ++nt) {
            int kpos = kbase + wk * 64 + nt * 16 + lane15;   // C/D col = lane&15
            float2v xf2 = (float2v)(float)(kpos % WIDTH);
            float2v yf2 = (float2v)(float)(kpos / WIDTH);
            #pragma unroll
            for (int mt = 0; mt < 4; ++mt) {
                #pragma unroll
                for (int rp = 0; rp < 2; ++rp) {             // C/D row = quad*4 + r
                    float2v lg;
                    lg.x = acc[mt][nt][2 * rp];
                    lg.y = acc[mt][nt][2 * rp + 1];
                    float2v e;
                    e.x = __builtin_exp2f(lg.x);
                    e.y = __builtin_exp2f(lg.y);
                    int p = mt * 2 + rp;
                    l2[p]  += e;
                    ax2[p] += e * xf2;
                    ay2[p] += e * yf2;
                    mx2[p] = __builtin_elementwise_max(mx2[p], lg);
                }
            }
        }
        __syncthreads();   // prefetch has landed (drain) & readers of cur done
    }

    // reduce over the 16 columns (lanes sharing a quad)
    #pragma unroll
    for (int p = 0; p < 8; ++p) {
        #pragma unroll
        for (int m = 1; m < 16; m <<= 1) {
            l2[p].x  += __shfl_xor(l2[p].x,  m, 64);
            l2[p].y  += __shfl_xor(l2[p].y,  m, 64);
            ax2[p].x += __shfl_xor(ax2[p].x, m, 64);
            ax2[p].y += __shfl_xor(ax2[p].y, m, 64);
            ay2[p].x += __shfl_xor(ay2[p].x, m, 64);
            ay2[p].y += __shfl_xor(ay2[p].y, m, 64);
            mx2[p].x  = fmaxf(mx2[p].x, __shfl_xor(mx2[p].x, m, 64));
            mx2[p].y  = fmaxf(mx2[p].y, __shfl_xor(mx2[p].y, m, 64));
        }
    }

    if (lane15 == 0) {
        #pragma unroll
        for (int p = 0; p < 8; ++p) {
            int mt = p >> 1, rp = p & 1;
            #pragma unroll
            for (int comp = 0; comp < 2; ++comp) {
                int r = 2 * rp + comp;
                int row = wq * 64 + mt * 16 + quad * 4 + r;
                float lv  = comp ? l2[p].y  : l2[p].x;
                float axv = comp ? ax2[p].y : ax2[p].x;
                float ayv = comp ? ay2[p].y : ay2[p].x;
                float mxv = __builtin_exp2f(comp ? mx2[p].y : mx2[p].x);
                part[((size_t)(b * HW + qt * 128 + row)) * 16 + split * 2 + wk] =
                    make_float4(lv, axv, ayv, mxv);
            }
        }
    }
}

// ---------------------------------------------------------------------------
// Kernel 3: combine 16 partials per query row, write flow + conf
// ---------------------------------------------------------------------------
__global__ __launch_bounds__(256) void combine_kernel(const float4* __restrict__ part,
                                                      float* __restrict__ out)
{
    int tid = blockIdx.x * 256 + threadIdx.x;   // 0 .. B*HW-1 (grid sized exactly)
    int b = tid / HW, pos = tid % HW;
    float l = 0.f, ax = 0.f, ay = 0.f, mx = 0.f;
    #pragma unroll
    for (int s = 0; s < 16; ++s) {
        float4 v = part[(size_t)tid * 16 + s];
        l += v.x; ax += v.y; ay += v.z; mx = fmaxf(mx, v.w);
    }
    float inv = 1.0f / l;
    int x = pos % WIDTH, y = pos / WIDTH;
    out[(size_t)b * 2 * HW + pos]           = ax * inv - (float)x;
    out[(size_t)b * 2 * HW + HW + pos]      = ay * inv - (float)y;
    out[(size_t)BATCH * 2 * HW + (size_t)b * HW + pos] = mx * inv;
}

// ---------------------------------------------------------------------------
extern "C" void kernel_launch(void* const* d_in, const int* in_sizes, int n_in,
                              void* d_out, int out_size, void* d_ws, size_t ws_size,
                              hipStream_t stream)
{
    const float* fL = (const float*)d_in[0];
    const float* fR = (const float*)d_in[1];
    float* out = (float*)d_out;

    char* ws = (char*)d_ws;
    const size_t QH_BYTES = (size_t)BATCH * HW * CDIM * sizeof(_Float16);  // 4.72 MB
    _Float16* Qh  = (_Float16*)ws;
    _Float16* Kh  = (_Float16*)(ws + QH_BYTES);
    float4*   part = (float4*)(ws + 2 * QH_BYTES);                         // 4.72 MB

    norm_kernel<<<dim3((BATCH * HW) / 256, 2), 256, 0, stream>>>(fL, fR, Qh, Kh);
    attn_kernel<<<dim3(HW / 128, 8, BATCH), 256, 0, stream>>>(Qh, Kh, part);
    combine_kernel<<<dim3((BATCH * HW) / 256), 256, 0, stream>>>(part, out);
}

// Round 3
// 155.790 us; speedup vs baseline: 1.1768x; 1.1768x over previous
//
#include <hip/hip_runtime.h>
#include <stdint.h>

#define HW 9216
#define CDIM 128
#define WIDTH 96
#define BATCH 2

// 1/(sqrt(128)*0.1) * log2(e): folded into Q so attn epilogue is a bare exp2
#define QSCALE 1.2753324954171245f

typedef _Float16 half8 __attribute__((ext_vector_type(8)));
typedef float float4v __attribute__((ext_vector_type(4)));
typedef float float2v __attribute__((ext_vector_type(2)));

// ---------------------------------------------------------------------------
// Kernel 1: L2-normalize over C, write fp16 [B][HW][C]. Tiled: block = 64
// positions x 128 channels, values kept in registers, output staged through
// padded LDS so global stores are fully coalesced 16B/lane.
// ---------------------------------------------------------------------------
__global__ __launch_bounds__(256) void norm_kernel(const float* __restrict__ fL,
                                                   const float* __restrict__ fR,
                                                   _Float16* __restrict__ Qh,
                                                   _Float16* __restrict__ Kh)
{
    __shared__ float ssred[4][64];
    __shared__ _Float16 ot[64 * 130];   // +2 halves pad -> bank advance 1/row

    const float* src = (blockIdx.y == 0) ? fL : fR;
    _Float16* dst    = (blockIdx.y == 0) ? Qh : Kh;
    const float outScale = (blockIdx.y == 0) ? QSCALE : 1.0f;

    const int t = threadIdx.x;
    const int pos_l = t & 63, cg = t >> 6;            // 4 channel groups of 32
    const int pos0 = blockIdx.x * 64;                  // 64 | HW so no straddle
    const int b = pos0 / HW, pos_in = pos0 % HW + pos_l;

    const float* p = src + (size_t)b * CDIM * HW + pos_in;

    float v[32];
    float ss = 0.f;
    #pragma unroll
    for (int j = 0; j < 32; ++j) {
        v[j] = p[(size_t)(cg * 32 + j) * HW];
        ss += v[j] * v[j];
    }
    ssred[cg][pos_l] = ss;
    __syncthreads();
    float tot = ssred[0][pos_l] + ssred[1][pos_l] + ssred[2][pos_l] + ssred[3][pos_l];
    float scale = outScale / fmaxf(sqrtf(tot), 1e-6f);

    #pragma unroll
    for (int j = 0; j < 32; ++j)
        ot[pos_l * 130 + cg * 32 + j] = (_Float16)(v[j] * scale);
    __syncthreads();

    // coalesced write-out: 16 KB tile, 4 x uint4 per thread
    uint4* og = (uint4*)(dst + (size_t)(b * HW + pos0 % HW + 0) * CDIM);
    #pragma unroll
    for (int i = 0; i < 4; ++i) {
        int idx = i * 256 + t;            // 0..1023 dwordx4 slots
        int row = idx >> 4, chunk = idx & 15;
        og[idx] = *(const uint4*)&ot[row * 130 + chunk * 8];
    }
}

// ---------------------------------------------------------------------------
// Kernel 2: fused correlation + softmax-accumulate.
// Block: 64 q-rows x 128-key split-stream, 4 waves as 2x2 of 32q x 32k.
// Q fragments in registers (32 VGPR), K double-buffered 2x16 KB LDS
// (XOR-chunk swizzle, global_load_lds width-16), ONE barrier per 64-key tile.
// Register budget ~110 -> no spills, 4 blocks/CU.
// No online max needed: |logit2| <= 1.28, exp2 in [0.41, 2.42].
// ---------------------------------------------------------------------------
__global__ __launch_bounds__(256, 4) void attn_kernel(const _Float16* __restrict__ Qh,
                                                      const _Float16* __restrict__ Kh,
                                                      float4* __restrict__ part)
{
    __shared__ _Float16 Ks[2][64 * 128];   // 2 x 16 KB

    const int qt = blockIdx.x, split = blockIdx.y, b = blockIdx.z;
    const int t = threadIdx.x;
    const int lane = t & 63, wave = t >> 6;
    const int wq = wave >> 1, wk = wave & 1;       // 2x2 waves over 64q x 64k
    const int lane15 = lane & 15, quad = lane >> 4;

    // ---- Q fragments direct from global (once per block): 8 x half8 = 32 VGPR
    half8 af[2][4];   // [mt][kc]
    {
        const char* qb = (const char*)(Qh +
            ((size_t)(b * HW + qt * 64 + wq * 32 + lane15)) * CDIM);
        #pragma unroll
        for (int mt = 0; mt < 2; ++mt)
            #pragma unroll
            for (int kc = 0; kc < 4; ++kc)
                af[mt][kc] = *(const half8*)(qb + mt * 16 * 256 + kc * 64 + quad * 16);
    }

    const char* kgb = (const char*)(Kh + (size_t)b * HW * CDIM);

    // stage one 64x128 K-tile (16 KB). dest linear (global_load_lds adds
    // lane*16); source chunk XOR-swizzled: LDS[r][c'] = K[r][c' ^ (r&15)].
    auto stage = [&](int kbase, int buf) {
        #pragma unroll
        for (int i = 0; i < 4; ++i) {
            int r = (wave * 4 + i) * 4 + quad;               // 0..63
            int schunk = lane15 ^ (r & 15);
            const void* src = kgb + (size_t)(kbase + r) * 256 + schunk * 16;
            _Float16* dstv = &Ks[buf][(wave * 4 + i) * 4 * 128];  // wave-uniform
            __builtin_amdgcn_global_load_lds(
                (const __attribute__((address_space(1))) uint32_t*)src,
                (__attribute__((address_space(3))) uint32_t*)dstv, 16, 0, 0);
        }
    };

    float2v l2[4], ax2[4], ay2[4], mx2[4];   // p = mt*2 + rpair
    #pragma unroll
    for (int p = 0; p < 4; ++p) {
        l2[p] = (float2v)0.f; ax2[p] = (float2v)0.f; ay2[p] = (float2v)0.f;
        mx2[p] = (float2v)(-1.0e30f);
    }

    const int kbase0 = split * 1152;
    stage(kbase0, 0);
    __syncthreads();

    for (int kt = 0; kt < 18; ++kt) {
        const int cur = kt & 1;
        const int kbase_g = kbase0 + kt * 64;

        float4v acc[2][2];
        #pragma unroll
        for (int mt = 0; mt < 2; ++mt)
            #pragma unroll
            for (int nt = 0; nt < 2; ++nt)
                acc[mt][nt] = (float4v)0.f;

        const char* kb = (const char*)&Ks[cur][0];
        #pragma unroll
        for (int kc = 0; kc < 4; ++kc) {
            half8 bf[2];
            #pragma unroll
            for (int nt = 0; nt < 2; ++nt) {
                int kr = wk * 32 + nt * 16 + lane15;          // kr & 15 == lane15
                bf[nt] = *(const half8*)(kb + (kr << 8) +
                                         (((kc * 4 + quad) ^ lane15) << 4));
            }
            #pragma unroll
            for (int mt = 0; mt < 2; ++mt)
                #pragma unroll
                for (int nt = 0; nt < 2; ++nt)
                    acc[mt][nt] = __builtin_amdgcn_mfma_f32_16x16x32_f16(
                        af[mt][kc], bf[nt], acc[mt][nt], 0, 0, 0);
        }

        // async prefetch of the next tile overlaps the VALU epilogue below
        if (kt < 17) stage(kbase_g + 64, 1 - cur);

        // ---- fused softmax-accumulate epilogue (packed fp32 pairs) ----
        #pragma unroll
        for (int nt = 0; nt < 2; ++nt) {
            int kpos = kbase_g + wk * 32 + nt * 16 + lane15;  // C/D col = lane&15
            float2v xf2 = (float2v)(float)(kpos % WIDTH);
            float2v yf2 = (float2v)(float)(kpos / WIDTH);
            #pragma unroll
            for (int mt = 0; mt < 2; ++mt) {
                #pragma unroll
                for (int rp = 0; rp < 2; ++rp) {              // C/D row = quad*4+r
                    float2v lg;
                    lg.x = acc[mt][nt][2 * rp];
                    lg.y = acc[mt][nt][2 * rp + 1];
                    float2v e;
                    e.x = __builtin_exp2f(lg.x);
                    e.y = __builtin_exp2f(lg.y);
                    int p = mt * 2 + rp;
                    l2[p]  += e;
                    ax2[p] += e * xf2;
                    ay2[p] += e * yf2;
                    mx2[p] = __builtin_elementwise_max(mx2[p], lg);
                }
            }
        }
        __syncthreads();   // readers of cur done + prefetch drained
    }

    // reduce over the 16 columns (lanes sharing a quad)
    #pragma unroll
    for (int p = 0; p < 4; ++p) {
        #pragma unroll
        for (int m = 1; m < 16; m <<= 1) {
            l2[p].x  += __shfl_xor(l2[p].x,  m, 64);
            l2[p].y  += __shfl_xor(l2[p].y,  m, 64);
            ax2[p].x += __shfl_xor(ax2[p].x, m, 64);
            ax2[p].y += __shfl_xor(ax2[p].y, m, 64);
            ay2[p].x += __shfl_xor(ay2[p].x, m, 64);
            ay2[p].y += __shfl_xor(ay2[p].y, m, 64);
            mx2[p].x  = fmaxf(mx2[p].x, __shfl_xor(mx2[p].x, m, 64));
            mx2[p].y  = fmaxf(mx2[p].y, __shfl_xor(mx2[p].y, m, 64));
        }
    }

    if (lane15 == 0) {
        #pragma unroll
        for (int p = 0; p < 4; ++p) {
            int mt = p >> 1, rp = p & 1;
            #pragma unroll
            for (int comp = 0; comp < 2; ++comp) {
                int r = 2 * rp + comp;
                int row = qt * 64 + wq * 32 + mt * 16 + quad * 4 + r;
                float lv  = comp ? l2[p].y  : l2[p].x;
                float axv = comp ? ax2[p].y : ax2[p].x;
                float ayv = comp ? ay2[p].y : ay2[p].x;
                float mxv = __builtin_exp2f(comp ? mx2[p].y : mx2[p].x);
                part[((size_t)(b * HW + row)) * 16 + split * 2 + wk] =
                    make_float4(lv, axv, ayv, mxv);
            }
        }
    }
}

// ---------------------------------------------------------------------------
// Kernel 3: combine 16 partials per query row, write flow + conf
// ---------------------------------------------------------------------------
__global__ __launch_bounds__(256) void combine_kernel(const float4* __restrict__ part,
                                                      float* __restrict__ out)
{
    int tid = blockIdx.x * 256 + threadIdx.x;   // 0 .. B*HW-1 (grid sized exactly)
    int b = tid / HW, pos = tid % HW;
    float l = 0.f, ax = 0.f, ay = 0.f, mx = 0.f;
    #pragma unroll
    for (int s = 0; s < 16; ++s) {
        float4 v = part[(size_t)tid * 16 + s];
        l += v.x; ax += v.y; ay += v.z; mx = fmaxf(mx, v.w);
    }
    float inv = 1.0f / l;
    int x = pos % WIDTH, y = pos / WIDTH;
    out[(size_t)b * 2 * HW + pos]           = ax * inv - (float)x;
    out[(size_t)b * 2 * HW + HW + pos]      = ay * inv - (float)y;
    out[(size_t)BATCH * 2 * HW + (size_t)b * HW + pos] = mx * inv;
}

// ---------------------------------------------------------------------------
extern "C" void kernel_launch(void* const* d_in, const int* in_sizes, int n_in,
                              void* d_out, int out_size, void* d_ws, size_t ws_size,
                              hipStream_t stream)
{
    const float* fL = (const float*)d_in[0];
    const float* fR = (const float*)d_in[1];
    float* out = (float*)d_out;

    char* ws = (char*)d_ws;
    const size_t QH_BYTES = (size_t)BATCH * HW * CDIM * sizeof(_Float16);  // 4.72 MB
    _Float16* Qh  = (_Float16*)ws;
    _Float16* Kh  = (_Float16*)(ws + QH_BYTES);
    float4*   part = (float4*)(ws + 2 * QH_BYTES);                         // 4.72 MB

    norm_kernel<<<dim3((BATCH * HW) / 64, 2), 256, 0, stream>>>(fL, fR, Qh, Kh);
    attn_kernel<<<dim3(HW / 64, 8, BATCH), 256, 0, stream>>>(Qh, Kh, part);
    combine_kernel<<<dim3((BATCH * HW) / 256), 256, 0, stream>>>(part, out);
}

// Round 4
// 142.417 us; speedup vs baseline: 1.2873x; 1.0939x over previous
//
#include <hip/hip_runtime.h>
#include <stdint.h>

#define HW 9216
#define CDIM 128
#define WIDTH 96
#define BATCH 2

// 1/(sqrt(128)*0.1) * log2(e): folded into Q so attn epilogue is a bare exp2
#define QSCALE 1.2753324954171245f

typedef _Float16 half8 __attribute__((ext_vector_type(8)));
typedef float float4v __attribute__((ext_vector_type(4)));
typedef float float2v __attribute__((ext_vector_type(2)));

// ---------------------------------------------------------------------------
// Kernel 1: L2-normalize over C, write fp16 [B][HW][C]. Tiled: block = 64
// positions x 128 channels, values kept in registers, output staged through
// padded LDS so global stores are fully coalesced 16B/lane.
// ---------------------------------------------------------------------------
__global__ __launch_bounds__(256) void norm_kernel(const float* __restrict__ fL,
                                                   const float* __restrict__ fR,
                                                   _Float16* __restrict__ Qh,
                                                   _Float16* __restrict__ Kh)
{
    __shared__ float ssred[4][64];
    __shared__ _Float16 ot[64 * 130];   // +2 halves pad -> bank advance 1/row

    const float* src = (blockIdx.y == 0) ? fL : fR;
    _Float16* dst    = (blockIdx.y == 0) ? Qh : Kh;
    const float outScale = (blockIdx.y == 0) ? QSCALE : 1.0f;

    const int t = threadIdx.x;
    const int pos_l = t & 63, cg = t >> 6;            // 4 channel groups of 32
    const int pos0 = blockIdx.x * 64;                  // 64 | HW so no straddle
    const int b = pos0 / HW, pos_in = pos0 % HW + pos_l;

    const float* p = src + (size_t)b * CDIM * HW + pos_in;

    float v[32];
    float ss = 0.f;
    #pragma unroll
    for (int j = 0; j < 32; ++j) {
        v[j] = p[(size_t)(cg * 32 + j) * HW];
        ss += v[j] * v[j];
    }
    ssred[cg][pos_l] = ss;
    __syncthreads();
    float tot = ssred[0][pos_l] + ssred[1][pos_l] + ssred[2][pos_l] + ssred[3][pos_l];
    float scale = outScale / fmaxf(sqrtf(tot), 1e-6f);

    #pragma unroll
    for (int j = 0; j < 32; ++j)
        ot[pos_l * 130 + cg * 32 + j] = (_Float16)(v[j] * scale);
    __syncthreads();

    // coalesced write-out: 16 KB tile, 4 x uint4 per thread
    uint4* og = (uint4*)(dst + (size_t)(b * HW + pos0 % HW + 0) * CDIM);
    #pragma unroll
    for (int i = 0; i < 4; ++i) {
        int idx = i * 256 + t;            // 0..1023 dwordx4 slots
        int row = idx >> 4, chunk = idx & 15;
        og[idx] = *(const uint4*)&ot[row * 130 + chunk * 8];
    }
}

// ---------------------------------------------------------------------------
// Kernel 2: fused correlation + softmax-accumulate.
// Block: 64 q-rows x 128-key split-stream, 4 waves as 2x2 of 32q x 32k.
// Q fragments in registers, K double-buffered 2x16 KB LDS (XOR-chunk
// swizzle, global_load_lds width-16), ONE barrier per 64-key tile.
// kt-loop FULLY UNROLLED (18 tiles): buffer index, coordinate phase
// (period 3: lcm(64,96)=192), and y-increment all compile-time constants.
// No online max needed: |logit2| <= 1.28.
// ---------------------------------------------------------------------------
__global__ __launch_bounds__(256, 4) void attn_kernel(const _Float16* __restrict__ Qh,
                                                      const _Float16* __restrict__ Kh,
                                                      float4* __restrict__ part)
{
    __shared__ _Float16 Ks[2][64 * 128];   // 2 x 16 KB

    const int qt = blockIdx.x, split = blockIdx.y, b = blockIdx.z;
    const int t = threadIdx.x;
    const int lane = t & 63, wave = t >> 6;
    const int wq = wave >> 1, wk = wave & 1;       // 2x2 waves over 64q x 64k
    const int lane15 = lane & 15, quad = lane >> 4;

    // ---- Q fragments direct from global (once per block): 8 x half8 = 32 VGPR
    half8 af[2][4];   // [mt][kc]
    {
        const char* qb = (const char*)(Qh +
            ((size_t)(b * HW + qt * 64 + wq * 32 + lane15)) * CDIM);
        #pragma unroll
        for (int mt = 0; mt < 2; ++mt)
            #pragma unroll
            for (int kc = 0; kc < 4; ++kc)
                af[mt][kc] = *(const half8*)(qb + mt * 16 * 256 + kc * 64 + quad * 16);
    }

    const int kbase0 = split * 1152;
    const char* kp0 = (const char*)(Kh + (size_t)b * HW * CDIM) + (size_t)kbase0 * 256;

    // fixed per-lane staging voffsets: wave handles rows [wave*16, wave*16+16)
    // LDS dest linear (instr adds lane*16B); source chunk XOR-swizzled so
    // LDS[r][c'] = K[r][c' ^ (r&15)] -> conflict-free fragment reads.
    int voff[4];
    #pragma unroll
    for (int i = 0; i < 4; ++i) {
        int r = wave * 16 + i * 4 + quad;
        voff[i] = r * 256 + ((lane15 ^ (r & 15)) << 4);
    }

    #define STAGE(TILE, BUF)                                                     \
        {                                                                        \
            const char* kb_ = kp0 + (TILE) * 16384;                              \
            _Float16* db_ = &Ks[BUF][wave * 16 * 128];                           \
            _Pragma("unroll")                                                    \
            for (int i_ = 0; i_ < 4; ++i_)                                       \
                __builtin_amdgcn_global_load_lds(                                \
                    (const __attribute__((address_space(1))) uint32_t*)(kb_ + voff[i_]), \
                    (__attribute__((address_space(3))) uint32_t*)(db_ + i_ * 4 * 128),   \
                    16, 0, 0);                                                   \
        }

    // ---- 3-phase coordinate tables (kbase0 % 96 == 0, period-3 in kt) ----
    // kpos(kt,nt) = kbase0 + kt*64 + off_nt ; x = (kt%3*64 + off_nt) % 96
    // y = split*12 + (kt%3*64 + off_nt)/96 + 2*(kt/3)
    float xph[3][2], yph[3][2];
    {
        int off0 = wk * 32 + lane15;
        #pragma unroll
        for (int p = 0; p < 3; ++p) {
            #pragma unroll
            for (int nt = 0; nt < 2; ++nt) {
                int k = p * 64 + off0 + nt * 16;
                xph[p][nt] = (float)(k % 96);
                yph[p][nt] = (float)(split * 12 + k / 96);
            }
        }
    }

    float2v l2[4], ax2[4], ay2[4], mx2[4];   // p = mt*2 + rpair (q-rows)
    #pragma unroll
    for (int p = 0; p < 4; ++p) {
        l2[p] = (float2v)0.f; ax2[p] = (float2v)0.f; ay2[p] = (float2v)0.f;
        mx2[p] = (float2v)(-1.0e30f);
    }

    STAGE(0, 0);
    __syncthreads();

    #pragma unroll
    for (int kt = 0; kt < 18; ++kt) {
        const int cur = kt & 1;              // compile-time
        const int phase = kt % 3;            // compile-time
        const float yadd = (float)(2 * (kt / 3));   // compile-time literal

        float4v acc[2][2];
        const char* kb = (const char*)&Ks[cur][0];
        #pragma unroll
        for (int kc = 0; kc < 4; ++kc) {
            half8 bf[2];
            #pragma unroll
            for (int nt = 0; nt < 2; ++nt) {
                int kr = wk * 32 + nt * 16 + lane15;          // kr & 15 == lane15
                bf[nt] = *(const half8*)(kb + (kr << 8) +
                                         (((kc * 4 + quad) ^ lane15) << 4));
            }
            #pragma unroll
            for (int mt = 0; mt < 2; ++mt)
                #pragma unroll
                for (int nt = 0; nt < 2; ++nt)
                    acc[mt][nt] = __builtin_amdgcn_mfma_f32_16x16x32_f16(
                        af[mt][kc], bf[nt],
                        (kc == 0) ? (float4v)0.f : acc[mt][nt], 0, 0, 0);
        }

        // async prefetch of the next tile overlaps the VALU epilogue below
        if (kt < 17) STAGE(kt + 1, 1 - cur);

        // ---- fused softmax-accumulate epilogue (packed fp32 pairs) ----
        #pragma unroll
        for (int nt = 0; nt < 2; ++nt) {
            float2v xf2 = (float2v)(xph[phase][nt]);
            float2v yf2 = (float2v)(yph[phase][nt] + yadd);
            #pragma unroll
            for (int mt = 0; mt < 2; ++mt) {
                #pragma unroll
                for (int rp = 0; rp < 2; ++rp) {              // C/D row = quad*4+r
                    float2v lg;
                    lg.x = acc[mt][nt][2 * rp];
                    lg.y = acc[mt][nt][2 * rp + 1];
                    float2v e;
                    e.x = __builtin_exp2f(lg.x);
                    e.y = __builtin_exp2f(lg.y);
                    int p = mt * 2 + rp;
                    l2[p]  += e;
                    ax2[p] += e * xf2;
                    ay2[p] += e * yf2;
                    mx2[p] = __builtin_elementwise_max(mx2[p], lg);
                }
            }
        }
        __syncthreads();   // readers of cur done + prefetch drained
    }

    // reduce over the 16 columns (lanes sharing a quad)
    #pragma unroll
    for (int p = 0; p < 4; ++p) {
        #pragma unroll
        for (int m = 1; m < 16; m <<= 1) {
            l2[p].x  += __shfl_xor(l2[p].x,  m, 64);
            l2[p].y  += __shfl_xor(l2[p].y,  m, 64);
            ax2[p].x += __shfl_xor(ax2[p].x, m, 64);
            ax2[p].y += __shfl_xor(ax2[p].y, m, 64);
            ay2[p].x += __shfl_xor(ay2[p].x, m, 64);
            ay2[p].y += __shfl_xor(ay2[p].y, m, 64);
            mx2[p].x  = fmaxf(mx2[p].x, __shfl_xor(mx2[p].x, m, 64));
            mx2[p].y  = fmaxf(mx2[p].y, __shfl_xor(mx2[p].y, m, 64));
        }
    }

    // part layout: [s=split*2+wk][b*HW + row] -> coalesced stores & loads
    if (lane15 == 0) {
        #pragma unroll
        for (int p = 0; p < 4; ++p) {
            int mt = p >> 1, rp = p & 1;
            #pragma unroll
            for (int comp = 0; comp < 2; ++comp) {
                int r = 2 * rp + comp;
                int row = qt * 64 + wq * 32 + mt * 16 + quad * 4 + r;
                float lv  = comp ? l2[p].y  : l2[p].x;
                float axv = comp ? ax2[p].y : ax2[p].x;
                float ayv = comp ? ay2[p].y : ay2[p].x;
                float mxv = __builtin_exp2f(comp ? mx2[p].y : mx2[p].x);
                part[(size_t)(split * 2 + wk) * (BATCH * HW) + b * HW + row] =
                    make_float4(lv, axv, ayv, mxv);
            }
        }
    }
    #undef STAGE
}

// ---------------------------------------------------------------------------
// Kernel 3: combine 16 partials per query row, write flow + conf
// ---------------------------------------------------------------------------
__global__ __launch_bounds__(256) void combine_kernel(const float4* __restrict__ part,
                                                      float* __restrict__ out)
{
    int tid = blockIdx.x * 256 + threadIdx.x;   // 0 .. B*HW-1 (grid sized exactly)
    int b = tid / HW, pos = tid % HW;
    float l = 0.f, ax = 0.f, ay = 0.f, mx = 0.f;
    #pragma unroll
    for (int s = 0; s < 16; ++s) {
        float4 v = part[(size_t)s * (BATCH * HW) + tid];   // coalesced
        l += v.x; ax += v.y; ay += v.z; mx = fmaxf(mx, v.w);
    }
    float inv = 1.0f / l;
    int x = pos % WIDTH, y = pos / WIDTH;
    out[(size_t)b * 2 * HW + pos]           = ax * inv - (float)x;
    out[(size_t)b * 2 * HW + HW + pos]      = ay * inv - (float)y;
    out[(size_t)BATCH * 2 * HW + (size_t)b * HW + pos] = mx * inv;
}

// ---------------------------------------------------------------------------
extern "C" void kernel_launch(void* const* d_in, const int* in_sizes, int n_in,
                              void* d_out, int out_size, void* d_ws, size_t ws_size,
                              hipStream_t stream)
{
    const float* fL = (const float*)d_in[0];
    const float* fR = (const float*)d_in[1];
    float* out = (float*)d_out;

    char* ws = (char*)d_ws;
    const size_t QH_BYTES = (size_t)BATCH * HW * CDIM * sizeof(_Float16);  // 4.72 MB
    _Float16* Qh  = (_Float16*)ws;
    _Float16* Kh  = (_Float16*)(ws + QH_BYTES);
    float4*   part = (float4*)(ws + 2 * QH_BYTES);                         // 4.72 MB

    norm_kernel<<<dim3((BATCH * HW) / 64, 2), 256, 0, stream>>>(fL, fR, Qh, Kh);
    attn_kernel<<<dim3(HW / 64, 8, BATCH), 256, 0, stream>>>(Qh, Kh, part);
    combine_kernel<<<dim3((BATCH * HW) / 256), 256, 0, stream>>>(part, out);
}